// Round 5
// baseline (489.147 us; speedup 1.0000x reference)
//
#include <hip/hip_runtime.h>

#define HIDDEN  128
#define REDUCED 64
#define NGRAPHS 4096

typedef float f4 __attribute__((ext_vector_type(4)));

// ---------------------------------------------------------------------------
// Prologue: starts[g] = lower_bound(batch, g). 4096 parallel binary searches
// fully overlap their dependent load chains; ~3 us. starts fully written ->
// workspace poison-safe.
// ---------------------------------------------------------------------------
__global__ void seg_starts_kernel(const int* __restrict__ batch,
                                  int* __restrict__ starts, int n_nodes) {
    const int g = blockIdx.x * blockDim.x + threadIdx.x;
    if (g >= NGRAPHS) return;
    int lo = 0, hi = n_nodes;
    while (lo < hi) { int mid = (lo + hi) >> 1; if (batch[mid] < g) lo = mid + 1; else hi = mid; }
    starts[g] = lo;
    if (g == 0) starts[NGRAPHS] = n_nodes;
}

// ---------------------------------------------------------------------------
// Fused per-graph pool + squeeze-excite MLP + modulate.
// ROUND-5 A/B EXPERIMENT: identical to the round-3 kernel (161 us, 79% occ,
// 3.07 TB/s effective) except ALL nontemporal hints are removed. Evidence
// from rounds 0/3/4: effective byte-rate fell monotonically (3.9 -> 3.0 ->
// 2.3 TB/s) as nt usage grew, while the normal-store fillBuffer sustains
// 6.4 TB/s; and round-3's nt re-read demoted x from L3 (FETCH=233MB/iter vs
// 126MB in round 4 which had no nt re-read). Theory: nt stores run well
// below the normal write path's rate, and nt loads evict-after-read.
// The L3-protection nt was buying is unnecessary: during modulate the live
// set is x[p:end] + out[0:p] ~= 244 MiB = constant, which fits the 256 MiB
// L3 even with allocating out-writes.
// Thread map: 256 thr = 8 row-slots (r = t>>5) x 32 f4-cols (c = t&31);
// pool and modulate iterate rows r, r+8, ... -> same summation order as the
// verified kernel, absmax unchanged.
// ---------------------------------------------------------------------------
__global__ void __launch_bounds__(256, 4)
fused_kernel(const float* __restrict__ x,
             const int* __restrict__ starts,
             const float* __restrict__ W1, const float* __restrict__ b1,
             const float* __restrict__ W2, const float* __restrict__ b2,
             float* __restrict__ out) {
    const int g = blockIdx.x;
    const int t = threadIdx.x;  // 256
    const int lo = starts[g], hi = starts[g + 1];  // coalesced broadcast
    const int r = t >> 5, c = t & 31;
    const f4* __restrict__ x4 = (const f4*)x;

    // ---- pool pass: allocating loads (x lands in L3 for the re-read) ----
    f4 acc = {0.f, 0.f, 0.f, 0.f};
    for (int n = lo + r; n < hi; n += 8) {
        acc += x4[(size_t)n * 32 + c];
    }

    __shared__ f4 red[8][32];
    __shared__ float p_s[HIDDEN];
    __shared__ float h_s[REDUCED];
    __shared__ float y_s[HIDDEN];
    red[r][c] = acc;
    __syncthreads();
    if (r == 0) {
        f4 s = red[0][c];
        #pragma unroll
        for (int k = 1; k < 8; ++k) s += red[k][c];
        ((f4*)p_s)[c] = s;
    }
    __syncthreads();

    // ---- MLP: h = relu(p @ W1 + b1) [64]; y = sigmoid(h @ W2 + b2) [128].
    // Same FMA order as the verified kernel; W1/W2 (48 KB) stay L2-resident.
    if (t < REDUCED) {
        float a1 = b1[t];
        #pragma unroll 8
        for (int i = 0; i < HIDDEN; ++i) a1 = fmaf(p_s[i], W1[i * REDUCED + t], a1);
        h_s[t] = a1 > 0.f ? a1 : 0.f;
    }
    __syncthreads();
    if (t < HIDDEN) {
        float a2 = b2[t];
        #pragma unroll 8
        for (int j = 0; j < REDUCED; ++j) a2 = fmaf(h_s[j], W2[j * HIDDEN + t], a2);
        y_s[t] = 1.f / (1.f + __expf(-a2));
    }
    __syncthreads();

    // ---- modulate pass: normal re-read (L3-hot from the pool pass),
    // normal allocating stores ----
    const f4 yv = ((const f4*)y_s)[c];
    f4* __restrict__ out4 = (f4*)out;
    for (int n = lo + r; n < hi; n += 8) {
        const f4 v = x4[(size_t)n * 32 + c];
        f4 o;
        o.x = v.x * yv.x; o.y = v.y * yv.y; o.z = v.z * yv.z; o.w = v.w * yv.w;
        out4[(size_t)n * 32 + c] = o;
    }
}

extern "C" void kernel_launch(void* const* d_in, const int* in_sizes, int n_in,
                              void* d_out, int out_size, void* d_ws, size_t ws_size,
                              hipStream_t stream) {
    const float* x     = (const float*)d_in[0];
    const int*   batch = (const int*)d_in[1];
    // d_in[2] is the scalar `size` (4096) — fixed-shape problem, hardcoded.
    const float* W1 = (const float*)d_in[3];
    const float* b1 = (const float*)d_in[4];
    const float* W2 = (const float*)d_in[5];
    const float* b2 = (const float*)d_in[6];
    float* out = (float*)d_out;

    const int n_nodes = in_sizes[0] / HIDDEN;

    int* starts = (int*)d_ws;  // 4097 ints, fully written by seg_starts_kernel

    seg_starts_kernel<<<(NGRAPHS + 255) / 256, 256, 0, stream>>>(batch, starts, n_nodes);
    fused_kernel<<<NGRAPHS, 256, 0, stream>>>(x, starts, W1, b1, W2, b2, out);
}

// Round 7
// 468.801 us; speedup vs baseline: 1.0434x; 1.0434x over previous
//
#include <hip/hip_runtime.h>

#define HIDDEN  128
#define REDUCED 64
#define NGRAPHS 4096
#define UF      8   // unroll factor = independent loads in flight per wave

typedef float f4 __attribute__((ext_vector_type(4)));

// ---------------------------------------------------------------------------
// Prologue: starts[g] = lower_bound(batch, g). 4096 parallel binary searches
// fully overlap their dependent load chains; ~3 us. starts fully written ->
// workspace poison-safe.
// ---------------------------------------------------------------------------
__global__ void seg_starts_kernel(const int* __restrict__ batch,
                                  int* __restrict__ starts, int n_nodes) {
    const int g = blockIdx.x * blockDim.x + threadIdx.x;
    if (g >= NGRAPHS) return;
    int lo = 0, hi = n_nodes;
    while (lo < hi) { int mid = (lo + hi) >> 1; if (batch[mid] < g) lo = mid + 1; else hi = mid; }
    starts[g] = lo;
    if (g == 0) starts[NGRAPHS] = n_nodes;
}

// ---------------------------------------------------------------------------
// Fused per-graph pool + squeeze-excite MLP + modulate.
// ROUND-7 = ROUND-6 RESUBMIT (round-6 bench died on container acquisition,
// not on the kernel). Identical to round 3 (best measured config: fused,
// L3-hot re-read, nt stores) except the pool and modulate loops are 8-way
// hand-unrolled. Evidence chain: r4 cut HBM traffic 24% -> no change; r3 vs
// r4 occupancy 79% vs 20% -> no change; VALUBusy ~5%; so the limiter is
// per-wave latency serialization. r3/r5 had VGPR_Count=12 -- one f4 load in
// flight per wave, each loop iteration a full vmcnt(0) memory round-trip
// (stores share vmcnt!). This version gives each wave UF=8 independent
// loads per wait in both hot loops; __launch_bounds__(256,2) gives the
// allocator room. OOB lanes are clamp-predicated (load row hi-1, add +0.f /
// mask the store) so the load batch issues unconditionally.
// Summation order per thread is unchanged (rows r, r+8, ... in sequence) ->
// pooled sums bitwise identical, absmax unchanged.
// ---------------------------------------------------------------------------
__global__ void __launch_bounds__(256, 2)
fused_kernel(const float* __restrict__ x,
             const int* __restrict__ starts,
             const float* __restrict__ W1, const float* __restrict__ b1,
             const float* __restrict__ W2, const float* __restrict__ b2,
             float* __restrict__ out) {
    const int g = blockIdx.x;
    const int t = threadIdx.x;  // 256
    const int lo = starts[g], hi = starts[g + 1];  // coalesced broadcast
    const int last = hi - 1;                       // clamp target (hi>lo when loops run)
    const int r = t >> 5, c = t & 31;
    const f4* __restrict__ x4 = (const f4*)x;

    // ---- pool pass: allocating loads (x lands in L3 for the re-read).
    // 8 independent loads issued per wait; +0.f for clamped tail lanes.
    f4 acc = {0.f, 0.f, 0.f, 0.f};
    for (int n0 = lo + r; n0 < hi; n0 += 8 * UF) {
        f4 v[UF];
        #pragma unroll
        for (int k = 0; k < UF; ++k) {
            const int n  = n0 + 8 * k;
            const int nc = n < hi ? n : last;             // always in-bounds
            v[k] = x4[(size_t)nc * 32 + c];
        }
        #pragma unroll
        for (int k = 0; k < UF; ++k) {
            const int n = n0 + 8 * k;
            const f4 z = {0.f, 0.f, 0.f, 0.f};
            acc += (n < hi) ? v[k] : z;                   // order preserved
        }
    }

    __shared__ f4 red[8][32];
    __shared__ float p_s[HIDDEN];
    __shared__ float h_s[REDUCED];
    __shared__ float y_s[HIDDEN];
    red[r][c] = acc;
    __syncthreads();
    if (r == 0) {
        f4 s = red[0][c];
        #pragma unroll
        for (int k = 1; k < 8; ++k) s += red[k][c];
        ((f4*)p_s)[c] = s;
    }
    __syncthreads();

    // ---- MLP: h = relu(p @ W1 + b1) [64]; y = sigmoid(h @ W2 + b2) [128].
    // Same FMA order as the verified kernel; W1/W2 (48 KB) stay L2-resident.
    if (t < REDUCED) {
        float a1 = b1[t];
        #pragma unroll 8
        for (int i = 0; i < HIDDEN; ++i) a1 = fmaf(p_s[i], W1[i * REDUCED + t], a1);
        h_s[t] = a1 > 0.f ? a1 : 0.f;
    }
    __syncthreads();
    if (t < HIDDEN) {
        float a2 = b2[t];
        #pragma unroll 8
        for (int j = 0; j < REDUCED; ++j) a2 = fmaf(h_s[j], W2[j * HIDDEN + t], a2);
        y_s[t] = 1.f / (1.f + __expf(-a2));
    }
    __syncthreads();

    // ---- modulate pass: re-read (L3-hot from the pool pass) with 8 loads
    // in flight, then 8 back-to-back nt stores (no allocation -> next
    // iteration's x stays L3-resident).
    const f4 yv = ((const f4*)y_s)[c];
    f4* __restrict__ out4 = (f4*)out;
    for (int n0 = lo + r; n0 < hi; n0 += 8 * UF) {
        f4 v[UF];
        #pragma unroll
        for (int k = 0; k < UF; ++k) {
            const int n  = n0 + 8 * k;
            const int nc = n < hi ? n : last;
            v[k] = x4[(size_t)nc * 32 + c];
        }
        #pragma unroll
        for (int k = 0; k < UF; ++k) {
            const int n = n0 + 8 * k;
            if (n < hi)
                __builtin_nontemporal_store(v[k] * yv, out4 + (size_t)n * 32 + c);
        }
    }
}

extern "C" void kernel_launch(void* const* d_in, const int* in_sizes, int n_in,
                              void* d_out, int out_size, void* d_ws, size_t ws_size,
                              hipStream_t stream) {
    const float* x     = (const float*)d_in[0];
    const int*   batch = (const int*)d_in[1];
    // d_in[2] is the scalar `size` (4096) — fixed-shape problem, hardcoded.
    const float* W1 = (const float*)d_in[3];
    const float* b1 = (const float*)d_in[4];
    const float* W2 = (const float*)d_in[5];
    const float* b2 = (const float*)d_in[6];
    float* out = (float*)d_out;

    const int n_nodes = in_sizes[0] / HIDDEN;

    int* starts = (int*)d_ws;  // 4097 ints, fully written by seg_starts_kernel

    seg_starts_kernel<<<(NGRAPHS + 255) / 256, 256, 0, stream>>>(batch, starts, n_nodes);
    fused_kernel<<<NGRAPHS, 256, 0, stream>>>(x, starts, W1, b1, W2, b2, out);
}